// Round 1
// 6070.673 us; speedup vs baseline: 3.2861x; 3.2861x over previous
//
#include <hip/hip_runtime.h>
#include <hip/hip_bf16.h>
#include <math.h>

#define B_ 16
#define L_ 100
#define D_ 512
#define HW_ 16384
#define H_ 8

using bf16x8 = __attribute__((ext_vector_type(8))) short;
using f32x4  = __attribute__((ext_vector_type(4))) float;

__device__ __forceinline__ unsigned short f2bf(float x) {
    unsigned u = __float_as_uint(x);
    u += 0x7fffu + ((u >> 16) & 1u);
    return (unsigned short)(u >> 16);
}
__device__ __forceinline__ float bf2f(unsigned short b) {
    return __uint_as_float(((unsigned)b) << 16);
}

// ---------------------------------------------------------------------------
// Generic tiled GEMM:  C = alpha*(A @ B^T) [+ bias] [+ residual] [relu]
// (unchanged from previous version)
// ---------------------------------------------------------------------------
__global__ __launch_bounds__(256) void gemm_bt(
    const float* __restrict__ A, const float* __restrict__ Bm,
    const float* __restrict__ Cres, const float* __restrict__ bias,
    float* __restrict__ C,
    int M, int N, int K, int lda, int ldb, int ldc,
    int zmod, long sA, long sB, long sC1, long sC2,
    float alpha, int relu)
{
    const int z = blockIdx.z;
    const long aOff = (long)z * sA;
    const long bOff = (long)(z % zmod) * sB;
    const long cOff = (long)(z / zmod) * sC1 + (long)(z % zmod) * sC2;

    __shared__ float As[16][65];
    __shared__ float Bs[16][65];

    const int tid = threadIdx.x;
    const int tx = tid & 15, ty = tid >> 4;
    const int m0 = blockIdx.y * 64, n0 = blockIdx.x * 64;
    const int lr = tid & 63;
    const int lk = (tid >> 6) * 4;

    float acc[4][4];
#pragma unroll
    for (int i = 0; i < 4; ++i)
#pragma unroll
        for (int j = 0; j < 4; ++j) acc[i][j] = 0.f;

    for (int k0 = 0; k0 < K; k0 += 16) {
        __syncthreads();
        {
            float4 v = make_float4(0.f, 0.f, 0.f, 0.f);
            const int gr = m0 + lr;
            if (gr < M) v = *(const float4*)&A[aOff + (long)gr * lda + k0 + lk];
            As[lk + 0][lr] = v.x; As[lk + 1][lr] = v.y;
            As[lk + 2][lr] = v.z; As[lk + 3][lr] = v.w;
            const float4 w = *(const float4*)&Bm[bOff + (long)(n0 + lr) * ldb + k0 + lk];
            Bs[lk + 0][lr] = w.x; Bs[lk + 1][lr] = w.y;
            Bs[lk + 2][lr] = w.z; Bs[lk + 3][lr] = w.w;
        }
        __syncthreads();
#pragma unroll
        for (int k = 0; k < 16; ++k) {
            float a[4], bb[4];
#pragma unroll
            for (int i = 0; i < 4; ++i) a[i] = As[k][ty + 16 * i];
#pragma unroll
            for (int j = 0; j < 4; ++j) bb[j] = Bs[k][tx + 16 * j];
#pragma unroll
            for (int i = 0; i < 4; ++i)
#pragma unroll
                for (int j = 0; j < 4; ++j) acc[i][j] += a[i] * bb[j];
        }
    }

#pragma unroll
    for (int i = 0; i < 4; ++i) {
        const int r = m0 + ty + 16 * i;
        if (r >= M) continue;
#pragma unroll
        for (int j = 0; j < 4; ++j) {
            const int c = n0 + tx + 16 * j;
            float vv = alpha * acc[i][j];
            if (bias) vv += bias[c];
            if (Cres) vv += Cres[cOff + (long)r * ldc + c];
            if (relu) vv = fmaxf(vv, 0.f);
            C[cOff + (long)r * ldc + c] = vv;
        }
    }
}

// ---------------------------------------------------------------------------
// qW[b,h,l,c] = sum_d q[b,l,h*64+d] * Wk[h*64+d, c]   (unchanged)
// ---------------------------------------------------------------------------
__global__ __launch_bounds__(256) void qw_kernel(
    const float* __restrict__ q, const float* __restrict__ Wk,
    float* __restrict__ qw)
{
    const int bz = blockIdx.x;
    const int b = bz >> 3, h = bz & 7;
    __shared__ float q_s[L_][64];

    const int tid = threadIdx.x;
#pragma unroll
    for (int t = 0; t < 25; ++t) {
        const int idx = tid + 256 * t;
        const int l = idx >> 6, d = idx & 63;
        q_s[l][d] = q[((long)(b * L_ + l)) * D_ + h * 64 + d];
    }
    __syncthreads();

    const float* Wh = Wk + (long)h * 64 * D_;
    for (int lb = 0; lb < 10; ++lb) {
        float acc0[10], acc1[10];
#pragma unroll
        for (int ll = 0; ll < 10; ++ll) { acc0[ll] = 0.f; acc1[ll] = 0.f; }
        for (int d = 0; d < 64; ++d) {
            const float w0 = Wh[(long)d * D_ + tid];
            const float w1 = Wh[(long)d * D_ + tid + 256];
#pragma unroll
            for (int ll = 0; ll < 10; ++ll) {
                const float qv = q_s[lb * 10 + ll][d];
                acc0[ll] += qv * w0;
                acc1[ll] += qv * w1;
            }
        }
#pragma unroll
        for (int ll = 0; ll < 10; ++ll) {
            const long o = (((long)(b * H_ + h)) * L_ + lb * 10 + ll) * D_;
            qw[o + tid] = acc0[ll];
            qw[o + tid + 256] = acc1[ll];
        }
    }
}

// ---------------------------------------------------------------------------
// MFMA flash attention. Per block: (b, 4 l's) -> 32 rows (8 heads x 4 l).
// Split-bf16 (hi/lo, 3-term) 16x16x32 MFMA for both QK^T and P@feats.
// 4 waves: wave = (mw = Mtile 0/1, nw = N parity).
// LDS 70.4 KB (overlaid regions) -> 2 blocks/CU.
// ---------------------------------------------------------------------------
#define MT_ 128

__global__ __launch_bounds__(256, 2) void flash_attn(
    const float* __restrict__ qw, const float* __restrict__ feats,
    float* __restrict__ ctx, float* __restrict__ mask_out)
{
    // LDS layout (bytes):
    //   [0, 33280)      qwlo  : ushort [32][520]
    //   [33280, 70144)  region1 (overlay):
    //       pass A:  fh ushort[128][72] (18432) | fl ushort[128][72] (18432)
    //       softmax: ssf float[32][132] (16896) | phl ushort[32][136] (8704)
    //                | pll ushort[32][136] (8704)
    //       pass B:  fth ushort[64][136] (17408) | ftl ushort[64][136] (17408)
    //   [70144, 70272)  alpha_s float[32]
    //   [70272, 70400)  sum_s   float[32]
    __shared__ __align__(16) char smem[70400];
    unsigned short* const qwlo = (unsigned short*)smem;
    char* const reg1 = smem + 33280;
    unsigned short* const fh  = (unsigned short*)reg1;
    unsigned short* const fl  = fh + 9216;
    float*          const ssf = (float*)reg1;
    unsigned short* const phl = (unsigned short*)(reg1 + 16896);
    unsigned short* const pll = phl + 4352;
    unsigned short* const fth = (unsigned short*)reg1;
    unsigned short* const ftl = fth + 8704;
    float* const alpha_s = (float*)(smem + 70144);
    float* const sum_s   = alpha_s + 32;

    const int tid  = threadIdx.x;
    const int lane = tid & 63;
    const int w    = tid >> 6;      // wave 0..3
    const int mw   = w >> 1;        // Mtile of this wave (rows mw*16..+15)
    const int nw   = w & 1;         // N-tile parity
    const int ln15 = lane & 15;
    const int kl8  = (lane >> 4) * 8;
    const int kl4  = (lane >> 4) * 4;

    const int blk = blockIdx.x;
    const int b   = blk / 25;
    const int l0  = (blk % 25) * 4;

    const f32x4 fzero = {0.f, 0.f, 0.f, 0.f};

    // ---- load qw A-fragments: hi -> registers, lo -> LDS ----
    const int hl_a = mw * 16 + ln15;            // A-fragment row (hl index)
    const int h_a = hl_a >> 2, li_a = hl_a & 3;
    const float* qrow = qw + (((long)(b * H_ + h_a)) * L_ + (l0 + li_a)) * D_;

    bf16x8 qhf[16];
#pragma unroll
    for (int kt = 0; kt < 16; ++kt) {
        float4 v0 = *(const float4*)&qrow[kt * 32 + kl8];
        float4 v1 = *(const float4*)&qrow[kt * 32 + kl8 + 4];
        float xs[8] = {v0.x, v0.y, v0.z, v0.w, v1.x, v1.y, v1.z, v1.w};
        bf16x8 qv;
        unsigned short ll[8];
#pragma unroll
        for (int e = 0; e < 8; ++e) {
            unsigned short hhv = f2bf(xs[e]);
            ll[e] = f2bf(xs[e] - bf2f(hhv));
            qv[e] = (short)hhv;
        }
        qhf[kt] = qv;
        if (nw == 0) {
            unsigned short* dst = &qwlo[hl_a * 520 + kt * 32 + kl8];
#pragma unroll
            for (int e = 0; e < 8; ++e) dst[e] = ll[e];
        }
    }

    float run_max = -INFINITY, run_sum = 0.f;
    const int srow = tid >> 3, slan = tid & 7;

    f32x4 cacc[8][2];   // [d-chunk][n-tile pair] per-wave ctx accumulators
#pragma unroll
    for (int i = 0; i < 8; ++i)
#pragma unroll
        for (int j = 0; j < 2; ++j) cacc[i][j] = fzero;

    const long fbase = (long)b * HW_ * D_;

    for (int m0 = 0; m0 < HW_; m0 += MT_) {
        // ================= pass A: S = qw @ feats^T =================
        f32x4 sacc[4];
#pragma unroll
        for (int t = 0; t < 4; ++t) sacc[t] = fzero;

#pragma unroll
        for (int dc = 0; dc < 8; ++dc) {
            __syncthreads();    // prev consumers of region1 done
            {
                float4 vv[8];
#pragma unroll
                for (int it = 0; it < 8; ++it) {
                    int f4 = tid + 256 * it;
                    int r = f4 >> 4, c4 = f4 & 15;
                    vv[it] = *(const float4*)&feats[fbase + (long)(m0 + r) * D_ + dc * 64 + c4 * 4];
                }
#pragma unroll
                for (int it = 0; it < 8; ++it) {
                    int f4 = tid + 256 * it;
                    int r = f4 >> 4, c4 = f4 & 15;
                    float xs[4] = {vv[it].x, vv[it].y, vv[it].z, vv[it].w};
                    unsigned short hh[4], ll[4];
#pragma unroll
                    for (int e = 0; e < 4; ++e) {
                        hh[e] = f2bf(xs[e]);
                        ll[e] = f2bf(xs[e] - bf2f(hh[e]));
                    }
                    uint2 hp, lp;
                    hp.x = (unsigned)hh[0] | ((unsigned)hh[1] << 16);
                    hp.y = (unsigned)hh[2] | ((unsigned)hh[3] << 16);
                    lp.x = (unsigned)ll[0] | ((unsigned)ll[1] << 16);
                    lp.y = (unsigned)ll[2] | ((unsigned)ll[3] << 16);
                    *(uint2*)&fh[r * 72 + c4 * 4] = hp;
                    *(uint2*)&fl[r * 72 + c4 * 4] = lp;
                }
            }
            __syncthreads();
#pragma unroll
            for (int kt = 0; kt < 2; ++kt) {
                bf16x8 qlv = *(const bf16x8*)&qwlo[hl_a * 520 + dc * 64 + kt * 32 + kl8];
                bf16x8 qhv = qhf[dc * 2 + kt];
#pragma unroll
                for (int t = 0; t < 4; ++t) {
                    const int nt = nw + 2 * t;
                    const unsigned short* bp = &fh[(nt * 16 + ln15) * 72 + kt * 32 + kl8];
                    bf16x8 bhv = *(const bf16x8*)bp;
                    bf16x8 blv = *(const bf16x8*)(bp + 9216);
                    sacc[t] = __builtin_amdgcn_mfma_f32_16x16x32_bf16(qhv, bhv, sacc[t], 0, 0, 0);
                    sacc[t] = __builtin_amdgcn_mfma_f32_16x16x32_bf16(qhv, blv, sacc[t], 0, 0, 0);
                    sacc[t] = __builtin_amdgcn_mfma_f32_16x16x32_bf16(qlv, bhv, sacc[t], 0, 0, 0);
                }
            }
        }

        __syncthreads();    // pass-A reads of fh/fl done -> region1 becomes ssf
        // ---- dump S (raw scores) to LDS ----
#pragma unroll
        for (int t = 0; t < 4; ++t) {
#pragma unroll
            for (int r = 0; r < 4; ++r)
                ssf[(mw * 16 + kl4 + r) * 132 + (nw + 2 * t) * 16 + ln15] = sacc[t][r];
        }
        __syncthreads();

        // ---- mask: sum of raw scores over heads ----
        {
            const int li = tid >> 6, mm = tid & 63;
#pragma unroll
            for (int rep = 0; rep < 2; ++rep) {
                const int m = mm + 64 * rep;
                float s = 0.f;
#pragma unroll
                for (int hh2 = 0; hh2 < 8; ++hh2) s += ssf[(hh2 * 4 + li) * 132 + m];
                mask_out[((long)(b * L_ + l0 + li)) * HW_ + m0 + m] = s;
            }
        }
        // (no barrier needed: softmax reads ssf, writes only phl/pll/alpha_s)

        // ---- online softmax per row; P -> bf16 hi/lo in LDS ----
        {
            float v[16];
            float mx = -INFINITY;
#pragma unroll
            for (int k = 0; k < 16; ++k) {
                v[k] = ssf[srow * 132 + slan * 16 + k];
                mx = fmaxf(mx, v[k]);
            }
#pragma unroll
            for (int o = 4; o > 0; o >>= 1) mx = fmaxf(mx, __shfl_xor(mx, o, 8));
            const float nm = fmaxf(run_max, mx);
            const float al = __expf(run_max - nm);
            float cs = 0.f;
            unsigned hp[8], lp[8];
#pragma unroll
            for (int j = 0; j < 8; ++j) {
                float p0 = __expf(v[2 * j]     - nm);
                float p1 = __expf(v[2 * j + 1] - nm);
                cs += p0 + p1;
                unsigned short h0 = f2bf(p0), h1 = f2bf(p1);
                unsigned short q0 = f2bf(p0 - bf2f(h0)), q1 = f2bf(p1 - bf2f(h1));
                hp[j] = (unsigned)h0 | ((unsigned)h1 << 16);
                lp[j] = (unsigned)q0 | ((unsigned)q1 << 16);
            }
            *(uint4*)&phl[srow * 136 + slan * 16]     = make_uint4(hp[0], hp[1], hp[2], hp[3]);
            *(uint4*)&phl[srow * 136 + slan * 16 + 8] = make_uint4(hp[4], hp[5], hp[6], hp[7]);
            *(uint4*)&pll[srow * 136 + slan * 16]     = make_uint4(lp[0], lp[1], lp[2], lp[3]);
            *(uint4*)&pll[srow * 136 + slan * 16 + 8] = make_uint4(lp[4], lp[5], lp[6], lp[7]);
#pragma unroll
            for (int o = 4; o > 0; o >>= 1) cs += __shfl_xor(cs, o, 8);
            run_sum = run_sum * al + cs;
            run_max = nm;
            if (slan == 0) alpha_s[srow] = al;
        }
        __syncthreads();

        // ---- load P fragments (kept in regs for all 8 d-chunks), rescale ctx ----
        bf16x8 pha[4], pla[4];
#pragma unroll
        for (int kt = 0; kt < 4; ++kt) {
            pha[kt] = *(const bf16x8*)&phl[(mw * 16 + ln15) * 136 + kt * 32 + kl8];
            pla[kt] = *(const bf16x8*)&pll[(mw * 16 + ln15) * 136 + kt * 32 + kl8];
        }
        float alr[4];
#pragma unroll
        for (int r = 0; r < 4; ++r) alr[r] = alpha_s[mw * 16 + kl4 + r];
#pragma unroll
        for (int i = 0; i < 8; ++i)
#pragma unroll
            for (int j = 0; j < 2; ++j)
#pragma unroll
                for (int r = 0; r < 4; ++r) cacc[i][j][r] *= alr[r];

        // ================= pass B: ctx += P @ feats =================
#pragma unroll
        for (int dc = 0; dc < 8; ++dc) {
            __syncthreads();   // P-frag loads (dc==0) / prev ft reads done
            {
                const int mq = tid & 15, dq = tid >> 4;
#pragma unroll
                for (int mh = 0; mh < 2; ++mh) {
                    float4 vv[4];
#pragma unroll
                    for (int i = 0; i < 4; ++i)
                        vv[i] = *(const float4*)&feats[fbase + (long)(m0 + mh * 64 + mq * 4 + i) * D_ + dc * 64 + dq * 4];
#pragma unroll
                    for (int j = 0; j < 4; ++j) {
                        unsigned short hh[4], ll[4];
#pragma unroll
                        for (int i = 0; i < 4; ++i) {
                            float x = ((const float*)&vv[i])[j];
                            hh[i] = f2bf(x);
                            ll[i] = f2bf(x - bf2f(hh[i]));
                        }
                        uint2 hp2, lp2;
                        hp2.x = (unsigned)hh[0] | ((unsigned)hh[1] << 16);
                        hp2.y = (unsigned)hh[2] | ((unsigned)hh[3] << 16);
                        lp2.x = (unsigned)ll[0] | ((unsigned)ll[1] << 16);
                        lp2.y = (unsigned)ll[2] | ((unsigned)ll[3] << 16);
                        *(uint2*)&fth[(dq * 4 + j) * 136 + mh * 64 + mq * 4] = hp2;
                        *(uint2*)&ftl[(dq * 4 + j) * 136 + mh * 64 + mq * 4] = lp2;
                    }
                }
            }
            __syncthreads();
#pragma unroll
            for (int kt = 0; kt < 4; ++kt) {
#pragma unroll
                for (int t = 0; t < 2; ++t) {
                    const int nt = nw + 2 * t;
                    const unsigned short* bp = &fth[(nt * 16 + ln15) * 136 + kt * 32 + kl8];
                    bf16x8 bhv = *(const bf16x8*)bp;
                    bf16x8 blv = *(const bf16x8*)(bp + 8704);
                    cacc[dc][t] = __builtin_amdgcn_mfma_f32_16x16x32_bf16(pha[kt], bhv, cacc[dc][t], 0, 0, 0);
                    cacc[dc][t] = __builtin_amdgcn_mfma_f32_16x16x32_bf16(pha[kt], blv, cacc[dc][t], 0, 0, 0);
                    cacc[dc][t] = __builtin_amdgcn_mfma_f32_16x16x32_bf16(pla[kt], bhv, cacc[dc][t], 0, 0, 0);
                }
            }
        }
    }

    // ---- writeout: normalize by softmax denominator ----
    if (slan == 0) sum_s[srow] = run_sum;
    __syncthreads();
#pragma unroll
    for (int r = 0; r < 4; ++r) {
        const int hl = mw * 16 + kl4 + r;
        const float inv = 1.f / sum_s[hl];
        const int h = hl >> 2, li = hl & 3;
        const long base = (((long)(b * H_ + h)) * L_ + (l0 + li)) * D_;
#pragma unroll
        for (int i = 0; i < 8; ++i)
#pragma unroll
            for (int j = 0; j < 2; ++j)
                ctx[base + i * 64 + (nw + 2 * j) * 16 + ln15] = cacc[i][j][r] * inv;
    }
}

// ---------------------------------------------------------------------------
// Row LayerNorm over 512 cols. One block per row. (unchanged)
// ---------------------------------------------------------------------------
__global__ __launch_bounds__(256) void ln_kernel(
    const float* __restrict__ X, const float* __restrict__ w,
    const float* __restrict__ bb, float* __restrict__ out)
{
    const int row = blockIdx.x;
    const int tid = threadIdx.x;
    const long base = (long)row * D_;
    const float x0 = X[base + tid];
    const float x1 = X[base + tid + 256];
    float s = x0 + x1;
    float sq = x0 * x0 + x1 * x1;
#pragma unroll
    for (int o = 32; o > 0; o >>= 1) {
        s  += __shfl_xor(s, o, 64);
        sq += __shfl_xor(sq, o, 64);
    }
    __shared__ float ws_[4], wq_[4];
    const int wid = tid >> 6, lane = tid & 63;
    if (lane == 0) { ws_[wid] = s; wq_[wid] = sq; }
    __syncthreads();
    s  = ws_[0] + ws_[1] + ws_[2] + ws_[3];
    sq = wq_[0] + wq_[1] + wq_[2] + wq_[3];
    const float mu = s * (1.f / 512.f);
    const float var = sq * (1.f / 512.f) - mu * mu;
    const float rs = rsqrtf(var + 1e-5f);
    out[base + tid]       = (x0 - mu) * rs * w[tid] + bb[tid];
    out[base + tid + 256] = (x1 - mu) * rs * w[tid + 256] + bb[tid + 256];
}

// ---------------------------------------------------------------------------
extern "C" void kernel_launch(void* const* d_in, const int* in_sizes, int n_in,
                              void* d_out, int out_size, void* d_ws, size_t ws_size,
                              hipStream_t stream)
{
    const float* query = (const float*)d_in[0];
    const float* feats = (const float*)d_in[1];
    const float* Wq    = (const float*)d_in[2];
    const float* Wk    = (const float*)d_in[3];
    const float* Wv    = (const float*)d_in[4];
    const float* Wp    = (const float*)d_in[5];
    const float* bp    = (const float*)d_in[6];
    const float* W1    = (const float*)d_in[7];
    const float* b1    = (const float*)d_in[8];
    const float* W2    = (const float*)d_in[9];
    const float* b2    = (const float*)d_in[10];
    const float* ln0w  = (const float*)d_in[11];
    const float* ln0b  = (const float*)d_in[12];
    const float* ln2w  = (const float*)d_in[13];
    const float* ln2b  = (const float*)d_in[14];

    float* out = (float*)d_out;            // [y: 819200][mask: 26214400]
    float* ws  = (float*)d_ws;

    // ws layout (floats). Total used: 13,926,400 floats = 53.2 MiB.
    float* q     = ws;                     //   819,200
    float* qw    = ws + 819200;            // 6,553,600
    float* ctx   = ws + 7372800;           // 6,553,600
    float* attno = ws;                     // reuse q region (dead after qw_kernel)
    float* xin   = ws + 7372800;           // reuse ctx region (dead after Wv proj)
    float* x     = xin + 819200;
    float* h1    = x + 819200;
    float* ffnp  = h1 + 819200;

    const dim3 thr(256);

    // q = 0.125 * query @ Wq.T        [1600 x 512, K=512]
    gemm_bt<<<dim3(8, 25, 1), thr, 0, stream>>>(
        query, Wq, nullptr, nullptr, q,
        1600, 512, 512, 512, 512, 512, 1, 0, 0, 0, 0, 0.125f, 0);

    // qW[b,h,l,:] = q_head @ Wk_head
    qw_kernel<<<dim3(128), thr, 0, stream>>>(q, Wk, qw);

    // fused scores + mask + online softmax + ctx accumulation (MFMA)
    flash_attn<<<dim3(400), thr, 0, stream>>>(qw, feats, ctx, out + 819200);

    // attno[b,l,h*64+d] = ctx[b,h,l,:] . Wv[h*64+d,:]  (batched over 128 (b,h))
    gemm_bt<<<dim3(1, 2, 128), thr, 0, stream>>>(
        ctx, Wv, nullptr, nullptr, attno,
        100, 64, 512, 512, 512, 512, 8, 51200, 32768, 51200, 64, 1.f, 0);

    // xin = query + attno @ Wp.T + bp
    gemm_bt<<<dim3(8, 25, 1), thr, 0, stream>>>(
        attno, Wp, query, bp, xin,
        1600, 512, 512, 512, 512, 512, 1, 0, 0, 0, 0, 1.f, 0);

    // x = LN0(xin)
    ln_kernel<<<dim3(1600), thr, 0, stream>>>(xin, ln0w, ln0b, x);

    // h1 = relu(x @ W1.T + b1)
    gemm_bt<<<dim3(8, 25, 1), thr, 0, stream>>>(
        x, W1, nullptr, b1, h1,
        1600, 512, 512, 512, 512, 512, 1, 0, 0, 0, 0, 1.f, 1);

    // ffnp = x + h1 @ W2.T + b2
    gemm_bt<<<dim3(8, 25, 1), thr, 0, stream>>>(
        h1, W2, x, b2, ffnp,
        1600, 512, 512, 512, 512, 512, 1, 0, 0, 0, 0, 1.f, 0);

    // y = LN2(ffnp) -> d_out
    ln_kernel<<<dim3(1600), thr, 0, stream>>>(ffnp, ln2w, ln2b, out);
}